// Round 1
// baseline (1217.772 us; speedup 1.0000x reference)
//
#include <hip/hip_runtime.h>
#include <stdint.h>

// Problem constants
#define Bsz 32
#define TKs 2048
#define Nf  1024
#define Msz (Bsz*TKs)   // 65536 = rows of the fused GEMM
#define KTOT 2048       // h (1024) concat q_h (1024)

typedef __bf16 bf16x8 __attribute__((ext_vector_type(8)));
typedef float  f32x4  __attribute__((ext_vector_type(4)));

// round-half-up fp32->bf16, two at a time, packed into one u32 (1 v_perm + 2 v_add)
__device__ __forceinline__ unsigned pack_bf2(float f0, float f1){
  unsigned u0 = __float_as_uint(f0) + 0x8000u;
  unsigned u1 = __float_as_uint(f1) + 0x8000u;
  return __builtin_amdgcn_perm(u1, u0, 0x07060302u);
}

__device__ __forceinline__ float fast_tanh(float x){
  x = fminf(15.f, fmaxf(-15.f, x));
  float e = __expf(2.f * x);
  return (e - 1.f) / (e + 1.f);
}

// ---------------------------------------------------------------------------
// Kernel 1: pack W_h||W_q (fp32 [1024][1024] each) -> Wcat bf16 [1024][2048]
// ---------------------------------------------------------------------------
__global__ __launch_bounds__(256) void pack_w_kernel(
    const float* __restrict__ Wh, const float* __restrict__ Wq,
    unsigned short* __restrict__ Wcat)
{
  int idx = (blockIdx.x * 256 + threadIdx.x) * 4;   // 4 elements / thread
  int m = idx >> 11;
  int k = idx & 2047;
  const float* src = (k < 1024) ? (Wh + m * 1024 + k) : (Wq + m * 1024 + (k - 1024));
  float4 v = *(const float4*)src;
  uint2 p;
  p.x = pack_bf2(v.x, v.y);
  p.y = pack_bf2(v.z, v.w);
  *(uint2*)(Wcat + idx) = p;
}

// ---------------------------------------------------------------------------
// Kernel 2: dec_feat[b][m] = dot(s_t_hat[b], W_d[m]) + b_d[m]   (fp32, exact)
// grid (16 m-chunks of 64, 32 b), 256 thr: wave handles 16 m's, lanes split n
// ---------------------------------------------------------------------------
__global__ __launch_bounds__(256) void dec_kernel(
    const float* __restrict__ s_t, const float* __restrict__ Wd,
    const float* __restrict__ bd, float* __restrict__ dec)
{
  __shared__ float sv[1024];
  const int b = blockIdx.y;
  const int mbase = blockIdx.x * 64;
  for (int i = threadIdx.x; i < 1024; i += 256) sv[i] = s_t[b * 1024 + i];
  __syncthreads();
  const int wave = threadIdx.x >> 6, lane = threadIdx.x & 63;
  #pragma unroll 4
  for (int i = 0; i < 16; ++i){
    int m = mbase + wave * 16 + i;
    const float4* wr = (const float4*)(Wd + (size_t)m * 1024 + lane * 16);
    const float4* sr = (const float4*)(sv + lane * 16);
    float s = 0.f;
    #pragma unroll
    for (int j = 0; j < 4; ++j){
      float4 w = wr[j], x = sr[j];
      s += w.x * x.x + w.y * x.y + w.z * x.z + w.w * x.w;
    }
    #pragma unroll
    for (int d = 1; d < 64; d <<= 1) s += __shfl_xor(s, d);
    if (lane == 0) dec[b * 1024 + m] = s + bd[m];
  }
}

// ---------------------------------------------------------------------------
// Kernel 3: fused GEMM + tanh + v-dot epilogue.
//   S[row, m] = sum_k A[row,k]*Wcat[m,k]   (A = h||q converted to bf16 on the fly)
//   scoresP[ntile][row] = sum_{m in tile} v_w[m]*tanh(S + dec[b,m] + cov[row]*W_c[m])
// 128x128 tile, BK=32, 16x16x32 bf16 MFMA, 4 waves in 2x2, 4x4 frags each.
// ---------------------------------------------------------------------------
#define AST 40   // padded LDS row stride (bf16 elems): 80B -> conflict-free-ish

__global__ __launch_bounds__(256) void gemm_fused(
    const float* __restrict__ h, const float* __restrict__ q,
    const unsigned short* __restrict__ Wcat,
    const float* __restrict__ dec, const float* __restrict__ cov,
    const float* __restrict__ Wc, const float* __restrict__ vw,
    float* __restrict__ scoresP)
{
  __shared__ unsigned short As[128 * AST];
  __shared__ unsigned short Bs[128 * AST];
  __shared__ float ssum[2][128];

  const int tid  = threadIdx.x;
  const int wave = tid >> 6, lane = tid & 63;
  const int wm = wave & 1, wn = wave >> 1;
  const int quad = lane >> 4, low = lane & 15;
  const int ntile = blockIdx.x;   // 8 n-tiles (fastest -> A-panel sharers concurrent)
  const int mtile = blockIdx.y;   // 512 m-tiles

  f32x4 acc[4][4];
  #pragma unroll
  for (int i = 0; i < 4; ++i)
    #pragma unroll
    for (int j = 0; j < 4; ++j) acc[i][j] = (f32x4){0.f, 0.f, 0.f, 0.f};

  // staging: thread covers half a 32-wide row (16 elems)
  const int sr = tid >> 1;
  const int sh = (tid & 1) * 16;
  const size_t a_goff = ((size_t)(mtile * 128 + sr)) * 1024 + sh;  // fp32 elems
  const size_t b_goff = ((size_t)(ntile * 128 + sr)) * 2048 + sh;  // bf16 elems
  unsigned short* a_st = &As[sr * AST + sh];
  unsigned short* b_st = &Bs[sr * AST + sh];

  // K-invariant fragment read pointers
  const bf16x8* a_rd[4];
  const bf16x8* b_rd[4];
  #pragma unroll
  for (int i = 0; i < 4; ++i){
    a_rd[i] = (const bf16x8*)&As[(wm * 64 + i * 16 + low) * AST + quad * 8];
    b_rd[i] = (const bf16x8*)&Bs[(wn * 64 + i * 16 + low) * AST + quad * 8];
  }

  for (int kt = 0; kt < KTOT / 32; ++kt){
    const int k0 = kt * 32;
    { // A stage: 16 fp32 -> 16 bf16, 2x ds_write_b128
      const float* src = (k0 < 1024) ? (h + a_goff + k0) : (q + a_goff + (k0 - 1024));
      float4 v0 = ((const float4*)src)[0];
      float4 v1 = ((const float4*)src)[1];
      float4 v2 = ((const float4*)src)[2];
      float4 v3 = ((const float4*)src)[3];
      uint4 p0, p1;
      p0.x = pack_bf2(v0.x, v0.y); p0.y = pack_bf2(v0.z, v0.w);
      p0.z = pack_bf2(v1.x, v1.y); p0.w = pack_bf2(v1.z, v1.w);
      p1.x = pack_bf2(v2.x, v2.y); p1.y = pack_bf2(v2.z, v2.w);
      p1.z = pack_bf2(v3.x, v3.y); p1.w = pack_bf2(v3.z, v3.w);
      ((uint4*)a_st)[0] = p0;
      ((uint4*)a_st)[1] = p1;
    }
    { // B stage: straight bf16 16B copies
      const uint4* src = (const uint4*)(Wcat + b_goff + k0);
      uint4 w0 = src[0];
      uint4 w1 = src[1];
      ((uint4*)b_st)[0] = w0;
      ((uint4*)b_st)[1] = w1;
    }
    __syncthreads();
    bf16x8 af[4], bg[4];
    #pragma unroll
    for (int i = 0; i < 4; ++i){ af[i] = *a_rd[i]; bg[i] = *b_rd[i]; }
    #pragma unroll
    for (int mi = 0; mi < 4; ++mi)
      #pragma unroll
      for (int ni = 0; ni < 4; ++ni)
        acc[mi][ni] = __builtin_amdgcn_mfma_f32_16x16x32_bf16(af[mi], bg[ni], acc[mi][ni], 0, 0, 0);
    __syncthreads();
  }

  // ---- epilogue: tanh + v-dot, reduce over this tile's 128 output-features ----
  const int brow = (mtile * 128) >> 11;           // batch idx (block-uniform: 2048%128==0)
  const float* decb = dec + brow * 1024;
  const int colbase = ntile * 128 + wn * 64 + low;
  float dv[4], wc4[4], vw4[4];
  #pragma unroll
  for (int ni = 0; ni < 4; ++ni){
    int col = colbase + ni * 16;
    dv[ni]  = decb[col];
    wc4[ni] = Wc[col];
    vw4[ni] = vw[col];
  }
  const size_t growbase = (size_t)mtile * 128;
  const int rowloc0 = wm * 64 + quad * 4;
  #pragma unroll
  for (int mi = 0; mi < 4; ++mi){
    #pragma unroll
    for (int r = 0; r < 4; ++r){
      int rl = rowloc0 + mi * 16 + r;            // C layout: row = quad*4 + reg
      float cv = cov[growbase + rl];
      float s = 0.f;
      #pragma unroll
      for (int ni = 0; ni < 4; ++ni){
        float x = acc[mi][ni][r] + dv[ni] + cv * wc4[ni];
        s += vw4[ni] * fast_tanh(x);
      }
      #pragma unroll
      for (int d = 1; d < 16; d <<= 1) s += __shfl_xor(s, d);  // reduce 16 cols/lane-group
      if (low == 0) ssum[wn][rl] = s;            // unique writer per (wn, rl)
    }
  }
  __syncthreads();
  if (tid < 128)
    scoresP[(size_t)ntile * Msz + growbase + tid] = ssum[0][tid] + ssum[1][tid];
}

// ---------------------------------------------------------------------------
// Kernel 4: masked renormalized softmax. attn = e*mask / sum(e*mask)
// (softmax denominator cancels algebraically). Also coverage_out.
// ---------------------------------------------------------------------------
__global__ __launch_bounds__(256) void softmax_kernel(
    const float* __restrict__ scoresP, const float* __restrict__ mask,
    const float* __restrict__ cov, float* __restrict__ attn_o,
    float* __restrict__ cov_o)
{
  const int b = blockIdx.x;
  const int tid = threadIdx.x;
  const int wave = tid >> 6, lane = tid & 63;
  __shared__ float redm[4], reds[4];
  float sc[8];
  float mx = -3.4e38f;
  #pragma unroll
  for (int j = 0; j < 8; ++j){
    int t = tid + j * 256;
    float s = 0.f;
    #pragma unroll
    for (int p = 0; p < 8; ++p) s += scoresP[(size_t)p * Msz + b * TKs + t];
    sc[j] = s;
    mx = fmaxf(mx, s);
  }
  #pragma unroll
  for (int d = 1; d < 64; d <<= 1) mx = fmaxf(mx, __shfl_xor(mx, d));
  if (lane == 0) redm[wave] = mx;
  __syncthreads();
  mx = fmaxf(fmaxf(redm[0], redm[1]), fmaxf(redm[2], redm[3]));
  float e[8]; float sum = 0.f;
  #pragma unroll
  for (int j = 0; j < 8; ++j){
    int t = tid + j * 256;
    float v = __expf(sc[j] - mx) * mask[b * TKs + t];
    e[j] = v; sum += v;
  }
  #pragma unroll
  for (int d = 1; d < 64; d <<= 1) sum += __shfl_xor(sum, d);
  if (lane == 0) reds[wave] = sum;
  __syncthreads();
  sum = reds[0] + reds[1] + reds[2] + reds[3];
  float inv = 1.f / sum;
  #pragma unroll
  for (int j = 0; j < 8; ++j){
    int t = tid + j * 256;
    float a = e[j] * inv;
    attn_o[b * TKs + t] = a;
    cov_o[b * TKs + t]  = cov[b * TKs + t] + a;
  }
}

// ---------------------------------------------------------------------------
// Kernel 5: c_t partials over t-chunks: P[tc][b][n] = sum_{t in chunk} attn*h
// grid (32 t-chunks of 64, 32 b)
// ---------------------------------------------------------------------------
__global__ __launch_bounds__(256) void ct_partial(
    const float* __restrict__ h, const float* __restrict__ attn,
    float* __restrict__ P)
{
  const int b = blockIdx.y, tc = blockIdx.x;
  const int n4 = threadIdx.x * 4;
  float4 acc = {0.f, 0.f, 0.f, 0.f};
  const float* hb = h + ((size_t)b * TKs + tc * 64) * Nf;
  const float* ab = attn + b * TKs + tc * 64;
  #pragma unroll 4
  for (int tt = 0; tt < 64; ++tt){
    float a = ab[tt];
    float4 hv = *(const float4*)(hb + (size_t)tt * Nf + n4);
    acc.x += a * hv.x; acc.y += a * hv.y; acc.z += a * hv.z; acc.w += a * hv.w;
  }
  *(float4*)(P + ((size_t)(tc * Bsz + b)) * Nf + n4) = acc;
}

__global__ __launch_bounds__(256) void ct_reduce(
    const float* __restrict__ P, float* __restrict__ out)
{
  int bn = (blockIdx.x * 256 + threadIdx.x) * 4;
  float4 s = {0.f, 0.f, 0.f, 0.f};
  for (int j = 0; j < 32; ++j){
    float4 v = *(const float4*)(P + (size_t)j * (Bsz * Nf) + bn);
    s.x += v.x; s.y += v.y; s.z += v.z; s.w += v.w;
  }
  *(float4*)(out + bn) = s;
}

// ---------------------------------------------------------------------------
extern "C" void kernel_launch(void* const* d_in, const int* in_sizes, int n_in,
                              void* d_out, int out_size, void* d_ws, size_t ws_size,
                              hipStream_t stream) {
  const float* s_t  = (const float*)d_in[0];
  const float* h    = (const float*)d_in[1];
  const float* mask = (const float*)d_in[2];
  const float* cov  = (const float*)d_in[3];
  const float* qh   = (const float*)d_in[4];
  const float* Wh   = (const float*)d_in[5];
  const float* Wq   = (const float*)d_in[6];
  const float* Wc   = (const float*)d_in[7];
  const float* Wd   = (const float*)d_in[8];
  const float* bd   = (const float*)d_in[9];
  const float* vw   = (const float*)d_in[10];

  float* out    = (float*)d_out;
  float* c_t    = out;                 // [32,1024]  = 32768
  float* attn_o = out + Bsz * Nf;      // [32,2048]  = 65536
  float* cov_o  = attn_o + Bsz * TKs;  // [32,2048]  = 65536

  char* ws = (char*)d_ws;
  unsigned short* Wcat = (unsigned short*)ws;                      // 4 MB
  float* dec     = (float*)(ws + (4u << 20));                      // 128 KB
  float* scoresP = (float*)(ws + (4u << 20) + (128u << 10));       // 8*65536*4 = 2 MB
  float* ctP     = (float*)(ws + (6u << 20) + (128u << 10));       // 32*32*1024*4 = 4 MB

  hipLaunchKernelGGL(pack_w_kernel, dim3(2048), dim3(256), 0, stream, Wh, Wq, Wcat);
  hipLaunchKernelGGL(dec_kernel,    dim3(16, 32), dim3(256), 0, stream, s_t, Wd, bd, dec);
  hipLaunchKernelGGL(gemm_fused,    dim3(8, 512), dim3(256), 0, stream,
                     h, qh, Wcat, dec, cov, Wc, vw, scoresP);
  hipLaunchKernelGGL(softmax_kernel, dim3(32), dim3(256), 0, stream,
                     scoresP, mask, cov, attn_o, cov_o);
  hipLaunchKernelGGL(ct_partial, dim3(32, 32), dim3(256), 0, stream, h, attn_o, ctP);
  hipLaunchKernelGGL(ct_reduce,  dim3(32), dim3(256), 0, stream, ctP, c_t);
}

// Round 2
// 991.991 us; speedup vs baseline: 1.2276x; 1.2276x over previous
//
#include <hip/hip_runtime.h>
#include <stdint.h>

// Problem constants
#define Bsz 32
#define TKs 2048
#define Nf  1024
#define Msz (Bsz*TKs)   // 65536 = rows of the fused GEMM
#define KTOT 2048       // h (1024) concat q_h (1024)

typedef __bf16 bf16x8 __attribute__((ext_vector_type(8)));
typedef float  f32x4  __attribute__((ext_vector_type(4)));

// round-half-up fp32->bf16, two at a time, packed into one u32
__device__ __forceinline__ unsigned pack_bf2(float f0, float f1){
  unsigned u0 = __float_as_uint(f0) + 0x8000u;
  unsigned u1 = __float_as_uint(f1) + 0x8000u;
  return __builtin_amdgcn_perm(u1, u0, 0x07060302u);
}

__device__ __forceinline__ float fast_tanh(float x){
  x = fminf(15.f, fmaxf(-15.f, x));
  float e = __expf(2.f * x);
  return (e - 1.f) / (e + 1.f);
}

// async global->LDS, 16B per lane. LDS dest = wave-uniform base + lane*16.
__device__ __forceinline__ void async16(void* lds, const void* g){
  __builtin_amdgcn_global_load_lds(
      (const __attribute__((address_space(1))) unsigned int*)g,
      (__attribute__((address_space(3))) unsigned int*)lds,
      16, 0, 0);
}

// ---------------------------------------------------------------------------
// Kernel 1: pack W_h||W_q (fp32 [1024][1024] each) -> Wcat bf16 [1024][2048]
// ---------------------------------------------------------------------------
__global__ __launch_bounds__(256) void pack_w_kernel(
    const float* __restrict__ Wh, const float* __restrict__ Wq,
    unsigned short* __restrict__ Wcat)
{
  int idx = (blockIdx.x * 256 + threadIdx.x) * 4;   // 4 elements / thread
  int m = idx >> 11;
  int k = idx & 2047;
  const float* src = (k < 1024) ? (Wh + m * 1024 + k) : (Wq + m * 1024 + (k - 1024));
  float4 v = *(const float4*)src;
  uint2 p;
  p.x = pack_bf2(v.x, v.y);
  p.y = pack_bf2(v.z, v.w);
  *(uint2*)(Wcat + idx) = p;
}

// ---------------------------------------------------------------------------
// Kernel 1b: pack A = h||q (fp32) -> Acat bf16 [65536][2048]
// ---------------------------------------------------------------------------
__global__ __launch_bounds__(256) void pack_a_kernel(
    const float* __restrict__ h, const float* __restrict__ q,
    unsigned short* __restrict__ Acat)
{
  size_t idx = ((size_t)blockIdx.x * 256 + threadIdx.x) * 8;   // 8 elems / thread
  size_t r = idx >> 11;
  int c = (int)(idx & 2047);
  const float* src = (c < 1024) ? (h + r * 1024 + c) : (q + r * 1024 + (c - 1024));
  float4 v0 = ((const float4*)src)[0];
  float4 v1 = ((const float4*)src)[1];
  uint4 p;
  p.x = pack_bf2(v0.x, v0.y); p.y = pack_bf2(v0.z, v0.w);
  p.z = pack_bf2(v1.x, v1.y); p.w = pack_bf2(v1.z, v1.w);
  *(uint4*)(Acat + idx) = p;
}

// ---------------------------------------------------------------------------
// Kernel 2: dec_feat[b][m] = dot(s_t_hat[b], W_d[m]) + b_d[m]   (fp32, exact)
// ---------------------------------------------------------------------------
__global__ __launch_bounds__(256) void dec_kernel(
    const float* __restrict__ s_t, const float* __restrict__ Wd,
    const float* __restrict__ bd, float* __restrict__ dec)
{
  __shared__ float sv[1024];
  const int b = blockIdx.y;
  const int mbase = blockIdx.x * 64;
  for (int i = threadIdx.x; i < 1024; i += 256) sv[i] = s_t[b * 1024 + i];
  __syncthreads();
  const int wave = threadIdx.x >> 6, lane = threadIdx.x & 63;
  #pragma unroll 4
  for (int i = 0; i < 16; ++i){
    int m = mbase + wave * 16 + i;
    const float4* wr = (const float4*)(Wd + (size_t)m * 1024 + lane * 16);
    const float4* sr = (const float4*)(sv + lane * 16);
    float s = 0.f;
    #pragma unroll
    for (int j = 0; j < 4; ++j){
      float4 w = wr[j], x = sr[j];
      s += w.x * x.x + w.y * x.y + w.z * x.z + w.w * x.w;
    }
    #pragma unroll
    for (int d = 1; d < 64; d <<= 1) s += __shfl_xor(s, d);
    if (lane == 0) dec[b * 1024 + m] = s + bd[m];
  }
}

// ---------------------------------------------------------------------------
// Kernel 3 (FAST): m97-style GEMM + tanh + v-dot epilogue.
// 128x128 tile, BK=32, global_load_lds width-16 staging (bf16 pre-packed A,B).
// LDS tiles contiguous 128x32 (no pad) as required by global_load_lds.
// Block swizzle: 8 n-tile sharers of one A-panel -> 8 consecutive slots on
// one XCD (assuming round-robin dispatch) for L2 A-reuse.
// ---------------------------------------------------------------------------
__global__ __launch_bounds__(256) void gemm_fused_fast(
    const unsigned short* __restrict__ Acat,
    const unsigned short* __restrict__ Wcat,
    const float* __restrict__ dec, const float* __restrict__ cov,
    const float* __restrict__ Wc, const float* __restrict__ vw,
    float* __restrict__ scoresP)
{
  __shared__ __align__(16) unsigned short As[128 * 32];
  __shared__ __align__(16) unsigned short Bs[128 * 32];
  __shared__ float ssum[2][128];

  const int tid  = threadIdx.x;
  const int wave = tid >> 6, lane = tid & 63;
  const int wm = wave & 1, wn = wave >> 1;
  const int quad = lane >> 4, low = lane & 15;

  const int p = blockIdx.x;
  const int ntile = (p >> 3) & 7;
  const int mtile = (p & 7) + ((p >> 6) << 3);

  f32x4 acc[4][4];
  #pragma unroll
  for (int i = 0; i < 4; ++i)
    #pragma unroll
    for (int j = 0; j < 4; ++j) acc[i][j] = (f32x4){0.f, 0.f, 0.f, 0.f};

  // staging: wave w, instruction j covers LDS 16B-slots [w*128 + j*64, +64),
  // lane l handles slot s = w*128 + j*64 + l;  row = s>>2, colgroup = s&3.
  const int s0 = wave * 128 + lane;
  const int s1 = s0 + 64;
  const unsigned short* pA0 = Acat + (size_t)(mtile * 128 + (s0 >> 2)) * 2048 + (s0 & 3) * 8;
  const unsigned short* pA1 = Acat + (size_t)(mtile * 128 + (s1 >> 2)) * 2048 + (s1 & 3) * 8;
  const unsigned short* pB0 = Wcat + (size_t)(ntile * 128 + (s0 >> 2)) * 2048 + (s0 & 3) * 8;
  const unsigned short* pB1 = Wcat + (size_t)(ntile * 128 + (s1 >> 2)) * 2048 + (s1 & 3) * 8;
  unsigned short* ldsA0 = &As[wave * 512];          // bytes: wave*1024
  unsigned short* ldsA1 = &As[wave * 512 + 256];    // + 512 B? no: elems
  // NOTE: 64 lanes * 16 B = 1024 B = 512 bf16 elems per instruction
  ldsA1 = &As[wave * 1024 + 512];
  ldsA0 = &As[wave * 1024];
  unsigned short* ldsB0 = &Bs[wave * 1024];
  unsigned short* ldsB1 = &Bs[wave * 1024 + 512];

  // K-invariant fragment read pointers (row stride 32 elems = 64 B)
  const bf16x8* a_rd[4];
  const bf16x8* b_rd[4];
  #pragma unroll
  for (int i = 0; i < 4; ++i){
    a_rd[i] = (const bf16x8*)&As[(wm * 64 + i * 16 + low) * 32 + quad * 8];
    b_rd[i] = (const bf16x8*)&Bs[(wn * 64 + i * 16 + low) * 32 + quad * 8];
  }

  for (int kt = 0; kt < KTOT / 32; ++kt){
    async16(ldsA0, pA0);
    async16(ldsA1, pA1);
    async16(ldsB0, pB0);
    async16(ldsB1, pB1);
    pA0 += 32; pA1 += 32; pB0 += 32; pB1 += 32;
    __syncthreads();
    bf16x8 af[4], bg[4];
    #pragma unroll
    for (int i = 0; i < 4; ++i){ af[i] = *a_rd[i]; bg[i] = *b_rd[i]; }
    #pragma unroll
    for (int mi = 0; mi < 4; ++mi)
      #pragma unroll
      for (int ni = 0; ni < 4; ++ni)
        acc[mi][ni] = __builtin_amdgcn_mfma_f32_16x16x32_bf16(af[mi], bg[ni], acc[mi][ni], 0, 0, 0);
    __syncthreads();
  }

  // ---- epilogue: tanh + v-dot, reduce over this tile's 128 output-features ----
  const int brow = (mtile * 128) >> 11;           // batch idx (block-uniform)
  const float* decb = dec + brow * 1024;
  const int colbase = ntile * 128 + wn * 64 + low;
  float dv[4], wc4[4], vw4[4];
  #pragma unroll
  for (int ni = 0; ni < 4; ++ni){
    int col = colbase + ni * 16;
    dv[ni]  = decb[col];
    wc4[ni] = Wc[col];
    vw4[ni] = vw[col];
  }
  const size_t growbase = (size_t)mtile * 128;
  const int rowloc0 = wm * 64 + quad * 4;
  #pragma unroll
  for (int mi = 0; mi < 4; ++mi){
    #pragma unroll
    for (int r = 0; r < 4; ++r){
      int rl = rowloc0 + mi * 16 + r;
      float cv = cov[growbase + rl];
      float s = 0.f;
      #pragma unroll
      for (int ni = 0; ni < 4; ++ni){
        float x = acc[mi][ni][r] + dv[ni] + cv * wc4[ni];
        s += vw4[ni] * fast_tanh(x);
      }
      #pragma unroll
      for (int d = 1; d < 16; d <<= 1) s += __shfl_xor(s, d);
      if (low == 0) ssum[wn][rl] = s;
    }
  }
  __syncthreads();
  if (tid < 128)
    scoresP[(size_t)ntile * Msz + growbase + tid] = ssum[0][tid] + ssum[1][tid];
}

// ---------------------------------------------------------------------------
// Kernel 3 (FALLBACK, proven R1): fused GEMM with in-loop fp32->bf16 staging
// ---------------------------------------------------------------------------
#define AST 40

__global__ __launch_bounds__(256) void gemm_fused_fb(
    const float* __restrict__ h, const float* __restrict__ q,
    const unsigned short* __restrict__ Wcat,
    const float* __restrict__ dec, const float* __restrict__ cov,
    const float* __restrict__ Wc, const float* __restrict__ vw,
    float* __restrict__ scoresP)
{
  __shared__ unsigned short As[128 * AST];
  __shared__ unsigned short Bs[128 * AST];
  __shared__ float ssum[2][128];

  const int tid  = threadIdx.x;
  const int wave = tid >> 6, lane = tid & 63;
  const int wm = wave & 1, wn = wave >> 1;
  const int quad = lane >> 4, low = lane & 15;
  const int ntile = blockIdx.x;
  const int mtile = blockIdx.y;

  f32x4 acc[4][4];
  #pragma unroll
  for (int i = 0; i < 4; ++i)
    #pragma unroll
    for (int j = 0; j < 4; ++j) acc[i][j] = (f32x4){0.f, 0.f, 0.f, 0.f};

  const int sr = tid >> 1;
  const int sh = (tid & 1) * 16;
  const size_t a_goff = ((size_t)(mtile * 128 + sr)) * 1024 + sh;
  const size_t b_goff = ((size_t)(ntile * 128 + sr)) * 2048 + sh;
  unsigned short* a_st = &As[sr * AST + sh];
  unsigned short* b_st = &Bs[sr * AST + sh];

  const bf16x8* a_rd[4];
  const bf16x8* b_rd[4];
  #pragma unroll
  for (int i = 0; i < 4; ++i){
    a_rd[i] = (const bf16x8*)&As[(wm * 64 + i * 16 + low) * AST + quad * 8];
    b_rd[i] = (const bf16x8*)&Bs[(wn * 64 + i * 16 + low) * AST + quad * 8];
  }

  for (int kt = 0; kt < KTOT / 32; ++kt){
    const int k0 = kt * 32;
    {
      const float* src = (k0 < 1024) ? (h + a_goff + k0) : (q + a_goff + (k0 - 1024));
      float4 v0 = ((const float4*)src)[0];
      float4 v1 = ((const float4*)src)[1];
      float4 v2 = ((const float4*)src)[2];
      float4 v3 = ((const float4*)src)[3];
      uint4 p0, p1;
      p0.x = pack_bf2(v0.x, v0.y); p0.y = pack_bf2(v0.z, v0.w);
      p0.z = pack_bf2(v1.x, v1.y); p0.w = pack_bf2(v1.z, v1.w);
      p1.x = pack_bf2(v2.x, v2.y); p1.y = pack_bf2(v2.z, v2.w);
      p1.z = pack_bf2(v3.x, v3.y); p1.w = pack_bf2(v3.z, v3.w);
      ((uint4*)a_st)[0] = p0;
      ((uint4*)a_st)[1] = p1;
    }
    {
      const uint4* src = (const uint4*)(Wcat + b_goff + k0);
      uint4 w0 = src[0];
      uint4 w1 = src[1];
      ((uint4*)b_st)[0] = w0;
      ((uint4*)b_st)[1] = w1;
    }
    __syncthreads();
    bf16x8 af[4], bg[4];
    #pragma unroll
    for (int i = 0; i < 4; ++i){ af[i] = *a_rd[i]; bg[i] = *b_rd[i]; }
    #pragma unroll
    for (int mi = 0; mi < 4; ++mi)
      #pragma unroll
      for (int ni = 0; ni < 4; ++ni)
        acc[mi][ni] = __builtin_amdgcn_mfma_f32_16x16x32_bf16(af[mi], bg[ni], acc[mi][ni], 0, 0, 0);
    __syncthreads();
  }

  const int brow = (mtile * 128) >> 11;
  const float* decb = dec + brow * 1024;
  const int colbase = ntile * 128 + wn * 64 + low;
  float dv[4], wc4[4], vw4[4];
  #pragma unroll
  for (int ni = 0; ni < 4; ++ni){
    int col = colbase + ni * 16;
    dv[ni]  = decb[col];
    wc4[ni] = Wc[col];
    vw4[ni] = vw[col];
  }
  const size_t growbase = (size_t)mtile * 128;
  const int rowloc0 = wm * 64 + quad * 4;
  #pragma unroll
  for (int mi = 0; mi < 4; ++mi){
    #pragma unroll
    for (int r = 0; r < 4; ++r){
      int rl = rowloc0 + mi * 16 + r;
      float cv = cov[growbase + rl];
      float s = 0.f;
      #pragma unroll
      for (int ni = 0; ni < 4; ++ni){
        float x = acc[mi][ni][r] + dv[ni] + cv * wc4[ni];
        s += vw4[ni] * fast_tanh(x);
      }
      #pragma unroll
      for (int d = 1; d < 16; d <<= 1) s += __shfl_xor(s, d);
      if (low == 0) ssum[wn][rl] = s;
    }
  }
  __syncthreads();
  if (tid < 128)
    scoresP[(size_t)ntile * Msz + growbase + tid] = ssum[0][tid] + ssum[1][tid];
}

// ---------------------------------------------------------------------------
// Kernel 4: masked renormalized softmax (softmax denom cancels) + coverage_out
// ---------------------------------------------------------------------------
__global__ __launch_bounds__(256) void softmax_kernel(
    const float* __restrict__ scoresP, const float* __restrict__ mask,
    const float* __restrict__ cov, float* __restrict__ attn_o,
    float* __restrict__ cov_o)
{
  const int b = blockIdx.x;
  const int tid = threadIdx.x;
  const int wave = tid >> 6, lane = tid & 63;
  __shared__ float redm[4], reds[4];
  float sc[8];
  float mx = -3.4e38f;
  #pragma unroll
  for (int j = 0; j < 8; ++j){
    int t = tid + j * 256;
    float s = 0.f;
    #pragma unroll
    for (int p = 0; p < 8; ++p) s += scoresP[(size_t)p * Msz + b * TKs + t];
    sc[j] = s;
    mx = fmaxf(mx, s);
  }
  #pragma unroll
  for (int d = 1; d < 64; d <<= 1) mx = fmaxf(mx, __shfl_xor(mx, d));
  if (lane == 0) redm[wave] = mx;
  __syncthreads();
  mx = fmaxf(fmaxf(redm[0], redm[1]), fmaxf(redm[2], redm[3]));
  float e[8]; float sum = 0.f;
  #pragma unroll
  for (int j = 0; j < 8; ++j){
    int t = tid + j * 256;
    float v = __expf(sc[j] - mx) * mask[b * TKs + t];
    e[j] = v; sum += v;
  }
  #pragma unroll
  for (int d = 1; d < 64; d <<= 1) sum += __shfl_xor(sum, d);
  if (lane == 0) reds[wave] = sum;
  __syncthreads();
  sum = reds[0] + reds[1] + reds[2] + reds[3];
  float inv = 1.f / sum;
  #pragma unroll
  for (int j = 0; j < 8; ++j){
    int t = tid + j * 256;
    float a = e[j] * inv;
    attn_o[b * TKs + t] = a;
    cov_o[b * TKs + t]  = cov[b * TKs + t] + a;
  }
}

// ---------------------------------------------------------------------------
// Kernel 5: c_t partials + reduce
// ---------------------------------------------------------------------------
__global__ __launch_bounds__(256) void ct_partial(
    const float* __restrict__ h, const float* __restrict__ attn,
    float* __restrict__ P)
{
  const int b = blockIdx.y, tc = blockIdx.x;
  const int n4 = threadIdx.x * 4;
  float4 acc = {0.f, 0.f, 0.f, 0.f};
  const float* hb = h + ((size_t)b * TKs + tc * 64) * Nf;
  const float* ab = attn + b * TKs + tc * 64;
  #pragma unroll 4
  for (int tt = 0; tt < 64; ++tt){
    float a = ab[tt];
    float4 hv = *(const float4*)(hb + (size_t)tt * Nf + n4);
    acc.x += a * hv.x; acc.y += a * hv.y; acc.z += a * hv.z; acc.w += a * hv.w;
  }
  *(float4*)(P + ((size_t)(tc * Bsz + b)) * Nf + n4) = acc;
}

__global__ __launch_bounds__(256) void ct_reduce(
    const float* __restrict__ P, float* __restrict__ out)
{
  int bn = (blockIdx.x * 256 + threadIdx.x) * 4;
  float4 s = {0.f, 0.f, 0.f, 0.f};
  for (int j = 0; j < 32; ++j){
    float4 v = *(const float4*)(P + (size_t)j * (Bsz * Nf) + bn);
    s.x += v.x; s.y += v.y; s.z += v.z; s.w += v.w;
  }
  *(float4*)(out + bn) = s;
}

// ---------------------------------------------------------------------------
extern "C" void kernel_launch(void* const* d_in, const int* in_sizes, int n_in,
                              void* d_out, int out_size, void* d_ws, size_t ws_size,
                              hipStream_t stream) {
  const float* s_t  = (const float*)d_in[0];
  const float* h    = (const float*)d_in[1];
  const float* mask = (const float*)d_in[2];
  const float* cov  = (const float*)d_in[3];
  const float* qh   = (const float*)d_in[4];
  const float* Wh   = (const float*)d_in[5];
  const float* Wq   = (const float*)d_in[6];
  const float* Wc   = (const float*)d_in[7];
  const float* Wd   = (const float*)d_in[8];
  const float* bd   = (const float*)d_in[9];
  const float* vw   = (const float*)d_in[10];

  float* out    = (float*)d_out;
  float* c_t    = out;                 // [32,1024]
  float* attn_o = out + Bsz * Nf;      // [32,2048]
  float* cov_o  = attn_o + Bsz * TKs;  // [32,2048]

  char* ws = (char*)d_ws;
  unsigned short* Wcat = (unsigned short*)ws;                      // 4 MB
  float* dec     = (float*)(ws + (4u << 20));                      // 128 KB
  float* scoresP = (float*)(ws + (4u << 20) + (128u << 10));       // 2 MB
  float* ctP     = (float*)(ws + (6u << 20) + (128u << 10));       // 4 MB
  unsigned short* Acat = (unsigned short*)(ws + (16ull << 20));    // 268.4 MB

  const size_t need_fast = (16ull << 20) + (size_t)Msz * KTOT * 2;
  const bool fast = (ws_size >= need_fast);

  hipLaunchKernelGGL(pack_w_kernel, dim3(2048), dim3(256), 0, stream, Wh, Wq, Wcat);
  hipLaunchKernelGGL(dec_kernel,    dim3(16, 32), dim3(256), 0, stream, s_t, Wd, bd, dec);
  if (fast){
    hipLaunchKernelGGL(pack_a_kernel, dim3((unsigned)((size_t)Msz * KTOT / 8 / 256)),
                       dim3(256), 0, stream, h, qh, Acat);
    hipLaunchKernelGGL(gemm_fused_fast, dim3(4096), dim3(256), 0, stream,
                       Acat, Wcat, dec, cov, Wc, vw, scoresP);
  } else {
    hipLaunchKernelGGL(gemm_fused_fb, dim3(8, 512), dim3(256), 0, stream,
                       h, qh, Wcat, dec, cov, Wc, vw, scoresP);
  }
  hipLaunchKernelGGL(softmax_kernel, dim3(32), dim3(256), 0, stream,
                     scoresP, mask, cov, attn_o, cov_o);
  hipLaunchKernelGGL(ct_partial, dim3(32, 32), dim3(256), 0, stream, h, attn_o, ctP);
  hipLaunchKernelGGL(ct_reduce,  dim3(32), dim3(256), 0, stream, ctP, c_t);
}

// Round 3
// 961.566 us; speedup vs baseline: 1.2664x; 1.0316x over previous
//
#include <hip/hip_runtime.h>
#include <stdint.h>

// Problem constants
#define Bsz 32
#define TKs 2048
#define Nf  1024
#define Msz (Bsz*TKs)   // 65536 = rows of the fused GEMM
#define KTOT 2048       // h (1024) concat q_h (1024)

typedef __bf16 bf16x8 __attribute__((ext_vector_type(8)));
typedef float  f32x4  __attribute__((ext_vector_type(4)));
typedef float  f32x16 __attribute__((ext_vector_type(16)));

// round-half-up fp32->bf16, two at a time, packed into one u32
__device__ __forceinline__ unsigned pack_bf2(float f0, float f1){
  unsigned u0 = __float_as_uint(f0) + 0x8000u;
  unsigned u1 = __float_as_uint(f1) + 0x8000u;
  return __builtin_amdgcn_perm(u1, u0, 0x07060302u);
}

// tanh without clamps: e=inf -> 1, e=0 -> -1 (graceful); v_rcp_f32 ~1ulp
__device__ __forceinline__ float fast_tanh(float x){
  float e = __expf(2.f * x);
  return 1.f - 2.f * __builtin_amdgcn_rcpf(e + 1.f);
}

// async global->LDS, 16B per lane. LDS dest = wave-uniform base + lane*16.
__device__ __forceinline__ void async16(void* lds, const void* g){
  __builtin_amdgcn_global_load_lds(
      (const __attribute__((address_space(1))) unsigned int*)g,
      (__attribute__((address_space(3))) unsigned int*)lds,
      16, 0, 0);
}

// ---------------------------------------------------------------------------
// Kernel 1: pack W_h||W_q (fp32 [1024][1024] each) -> Wcat bf16 [1024][2048]
// ---------------------------------------------------------------------------
__global__ __launch_bounds__(256) void pack_w_kernel(
    const float* __restrict__ Wh, const float* __restrict__ Wq,
    unsigned short* __restrict__ Wcat)
{
  int idx = (blockIdx.x * 256 + threadIdx.x) * 4;
  int m = idx >> 11;
  int k = idx & 2047;
  const float* src = (k < 1024) ? (Wh + m * 1024 + k) : (Wq + m * 1024 + (k - 1024));
  float4 v = *(const float4*)src;
  uint2 p;
  p.x = pack_bf2(v.x, v.y);
  p.y = pack_bf2(v.z, v.w);
  *(uint2*)(Wcat + idx) = p;
}

// ---------------------------------------------------------------------------
// Kernel 1b: pack A = h||q (fp32) -> Acat bf16 [65536][2048]
// ---------------------------------------------------------------------------
__global__ __launch_bounds__(256) void pack_a_kernel(
    const float* __restrict__ h, const float* __restrict__ q,
    unsigned short* __restrict__ Acat)
{
  size_t idx = ((size_t)blockIdx.x * 256 + threadIdx.x) * 8;
  size_t r = idx >> 11;
  int c = (int)(idx & 2047);
  const float* src = (c < 1024) ? (h + r * 1024 + c) : (q + r * 1024 + (c - 1024));
  float4 v0 = ((const float4*)src)[0];
  float4 v1 = ((const float4*)src)[1];
  uint4 p;
  p.x = pack_bf2(v0.x, v0.y); p.y = pack_bf2(v0.z, v0.w);
  p.z = pack_bf2(v1.x, v1.y); p.w = pack_bf2(v1.z, v1.w);
  *(uint4*)(Acat + idx) = p;
}

// ---------------------------------------------------------------------------
// Kernel 2: dec_feat[b][m] = dot(s_t_hat[b], W_d[m]) + b_d[m]   (fp32, exact)
// ---------------------------------------------------------------------------
__global__ __launch_bounds__(256) void dec_kernel(
    const float* __restrict__ s_t, const float* __restrict__ Wd,
    const float* __restrict__ bd, float* __restrict__ dec)
{
  __shared__ float sv[1024];
  const int b = blockIdx.y;
  const int mbase = blockIdx.x * 64;
  for (int i = threadIdx.x; i < 1024; i += 256) sv[i] = s_t[b * 1024 + i];
  __syncthreads();
  const int wave = threadIdx.x >> 6, lane = threadIdx.x & 63;
  #pragma unroll 4
  for (int i = 0; i < 16; ++i){
    int m = mbase + wave * 16 + i;
    const float4* wr = (const float4*)(Wd + (size_t)m * 1024 + lane * 16);
    const float4* sr = (const float4*)(sv + lane * 16);
    float s = 0.f;
    #pragma unroll
    for (int j = 0; j < 4; ++j){
      float4 w = wr[j], x = sr[j];
      s += w.x * x.x + w.y * x.y + w.z * x.z + w.w * x.w;
    }
    #pragma unroll
    for (int d = 1; d < 64; d <<= 1) s += __shfl_xor(s, d);
    if (lane == 0) dec[b * 1024 + m] = s + bd[m];
  }
}

// ---------------------------------------------------------------------------
// Kernel 3 (FAST): 32x32x16-MFMA GEMM + tanh + v-dot epilogue.
// 128x128 tile, BK=32, global_load_lds width-16 staging, XOR bank swizzle:
//   k-group g of row r lives at LDS position g ^ ((r>>1)&3)  -> 2-way (free).
// Wave (wm,wn) computes 64x64 = 2x2 tiles of 32x32, 8 MFMA / kt.
// ---------------------------------------------------------------------------
__global__ __launch_bounds__(256) void gemm_fused_fast(
    const unsigned short* __restrict__ Acat,
    const unsigned short* __restrict__ Wcat,
    const float* __restrict__ dec, const float* __restrict__ cov,
    const float* __restrict__ Wc, const float* __restrict__ vw,
    float* __restrict__ scoresP)
{
  __shared__ __align__(16) unsigned short As[128 * 32];
  __shared__ __align__(16) unsigned short Bs[128 * 32];
  __shared__ float ssum[2][128];
  __shared__ float covS[128];

  const int tid  = threadIdx.x;
  const int wave = tid >> 6, lane = tid & 63;
  const int wm = wave & 1, wn = wave >> 1;
  const int l31 = lane & 31, half = lane >> 5;

  const int p = blockIdx.x;
  const int ntile = (p >> 3) & 7;
  const int mtile = (p & 7) + ((p >> 6) << 3);
  const size_t growbase = (size_t)mtile * 128;

  if (tid < 128) covS[tid] = cov[growbase + tid];

  f32x16 acc[2][2];
  #pragma unroll
  for (int i = 0; i < 2; ++i)
    #pragma unroll
    for (int j = 0; j < 2; ++j)
      #pragma unroll
      for (int r = 0; r < 16; ++r) acc[i][j][r] = 0.f;

  // ---- staging source pointers (lane covers LDS slot s; swizzled source) ----
  const int s0 = wave * 128 + lane;          // 16B slots, 512 per tile
  const int s1 = s0 + 64;
  const int r0 = s0 >> 2, g0 = (s0 & 3) ^ ((r0 >> 1) & 3);
  const int r1 = s1 >> 2, g1 = (s1 & 3) ^ ((r1 >> 1) & 3);
  const unsigned short* pA0 = Acat + (size_t)(mtile * 128 + r0) * 2048 + g0 * 8;
  const unsigned short* pA1 = Acat + (size_t)(mtile * 128 + r1) * 2048 + g1 * 8;
  const unsigned short* pB0 = Wcat + (size_t)(ntile * 128 + r0) * 2048 + g0 * 8;
  const unsigned short* pB1 = Wcat + (size_t)(ntile * 128 + r1) * 2048 + g1 * 8;
  unsigned short* ldsA0 = &As[wave * 1024];
  unsigned short* ldsA1 = &As[wave * 1024 + 512];
  unsigned short* ldsB0 = &Bs[wave * 1024];
  unsigned short* ldsB1 = &Bs[wave * 1024 + 512];

  // ---- K-invariant fragment read pointers (swizzled) ----
  // A[m = l31 (+mi*32 +wm*64)][k = (ks*2+half)*8 .. +8]
  const bf16x8* a_rd[2][2];
  const bf16x8* b_rd[2][2];
  #pragma unroll
  for (int mi = 0; mi < 2; ++mi)
    #pragma unroll
    for (int ks = 0; ks < 2; ++ks){
      int row = wm * 64 + mi * 32 + l31;
      int g = ks * 2 + half;
      int pos = g ^ ((row >> 1) & 3);
      a_rd[mi][ks] = (const bf16x8*)&As[row * 32 + pos * 8];
    }
  #pragma unroll
  for (int ni = 0; ni < 2; ++ni)
    #pragma unroll
    for (int ks = 0; ks < 2; ++ks){
      int row = wn * 64 + ni * 32 + l31;
      int g = ks * 2 + half;
      int pos = g ^ ((row >> 1) & 3);
      b_rd[ni][ks] = (const bf16x8*)&Bs[row * 32 + pos * 8];
    }

  for (int kt = 0; kt < KTOT / 32; ++kt){
    async16(ldsA0, pA0);
    async16(ldsA1, pA1);
    async16(ldsB0, pB0);
    async16(ldsB1, pB1);
    pA0 += 32; pA1 += 32; pB0 += 32; pB1 += 32;
    __syncthreads();
    bf16x8 af[2][2], bg[2][2];
    #pragma unroll
    for (int i = 0; i < 2; ++i)
      #pragma unroll
      for (int ks = 0; ks < 2; ++ks){ af[i][ks] = *a_rd[i][ks]; bg[i][ks] = *b_rd[i][ks]; }
    #pragma unroll
    for (int ks = 0; ks < 2; ++ks)
      #pragma unroll
      for (int mi = 0; mi < 2; ++mi)
        #pragma unroll
        for (int ni = 0; ni < 2; ++ni)
          acc[mi][ni] = __builtin_amdgcn_mfma_f32_32x32x16_bf16(
              af[mi][ks], bg[ni][ks], acc[mi][ni], 0, 0, 0);
    __syncthreads();
  }

  // ---- epilogue: tanh + v-dot; C/D: col=lane&31, row=(r&3)+8*(r>>2)+4*half ----
  const int brow = (mtile * 128) >> 11;
  const float* decb = dec + brow * 1024;
  float dv[2], wc2[2], vw2[2];
  #pragma unroll
  for (int ni = 0; ni < 2; ++ni){
    int col = ntile * 128 + wn * 64 + ni * 32 + l31;
    dv[ni]  = decb[col];
    wc2[ni] = Wc[col];
    vw2[ni] = vw[col];
  }
  #pragma unroll
  for (int mi = 0; mi < 2; ++mi){
    #pragma unroll
    for (int r = 0; r < 16; ++r){
      int rl = wm * 64 + mi * 32 + (r & 3) + 8 * (r >> 2) + 4 * half;
      float cv = covS[rl];
      float s = 0.f;
      #pragma unroll
      for (int ni = 0; ni < 2; ++ni){
        float x = acc[mi][ni][r] + dv[ni] + cv * wc2[ni];
        s += vw2[ni] * fast_tanh(x);
      }
      #pragma unroll
      for (int d = 1; d < 32; d <<= 1) s += __shfl_xor(s, d);  // within 32-lane half
      if (l31 == 0) ssum[wn][rl] = s;
    }
  }
  __syncthreads();
  if (tid < 128)
    scoresP[(size_t)ntile * Msz + growbase + tid] = ssum[0][tid] + ssum[1][tid];
}

// ---------------------------------------------------------------------------
// Kernel 3 (FALLBACK, proven R1): fused GEMM with in-loop fp32->bf16 staging
// ---------------------------------------------------------------------------
#define AST 40

__global__ __launch_bounds__(256) void gemm_fused_fb(
    const float* __restrict__ h, const float* __restrict__ q,
    const unsigned short* __restrict__ Wcat,
    const float* __restrict__ dec, const float* __restrict__ cov,
    const float* __restrict__ Wc, const float* __restrict__ vw,
    float* __restrict__ scoresP)
{
  __shared__ unsigned short As[128 * AST];
  __shared__ unsigned short Bs[128 * AST];
  __shared__ float ssum[2][128];

  const int tid  = threadIdx.x;
  const int wave = tid >> 6, lane = tid & 63;
  const int wm = wave & 1, wn = wave >> 1;
  const int quad = lane >> 4, low = lane & 15;
  const int ntile = blockIdx.x;
  const int mtile = blockIdx.y;

  f32x4 acc[4][4];
  #pragma unroll
  for (int i = 0; i < 4; ++i)
    #pragma unroll
    for (int j = 0; j < 4; ++j) acc[i][j] = (f32x4){0.f, 0.f, 0.f, 0.f};

  const int sr = tid >> 1;
  const int sh = (tid & 1) * 16;
  const size_t a_goff = ((size_t)(mtile * 128 + sr)) * 1024 + sh;
  const size_t b_goff = ((size_t)(ntile * 128 + sr)) * 2048 + sh;
  unsigned short* a_st = &As[sr * AST + sh];
  unsigned short* b_st = &Bs[sr * AST + sh];

  const bf16x8* a_rd[4];
  const bf16x8* b_rd[4];
  #pragma unroll
  for (int i = 0; i < 4; ++i){
    a_rd[i] = (const bf16x8*)&As[(wm * 64 + i * 16 + low) * AST + quad * 8];
    b_rd[i] = (const bf16x8*)&Bs[(wn * 64 + i * 16 + low) * AST + quad * 8];
  }

  for (int kt = 0; kt < KTOT / 32; ++kt){
    const int k0 = kt * 32;
    {
      const float* src = (k0 < 1024) ? (h + a_goff + k0) : (q + a_goff + (k0 - 1024));
      float4 v0 = ((const float4*)src)[0];
      float4 v1 = ((const float4*)src)[1];
      float4 v2 = ((const float4*)src)[2];
      float4 v3 = ((const float4*)src)[3];
      uint4 p0, p1;
      p0.x = pack_bf2(v0.x, v0.y); p0.y = pack_bf2(v0.z, v0.w);
      p0.z = pack_bf2(v1.x, v1.y); p0.w = pack_bf2(v1.z, v1.w);
      p1.x = pack_bf2(v2.x, v2.y); p1.y = pack_bf2(v2.z, v2.w);
      p1.z = pack_bf2(v3.x, v3.y); p1.w = pack_bf2(v3.z, v3.w);
      ((uint4*)a_st)[0] = p0;
      ((uint4*)a_st)[1] = p1;
    }
    {
      const uint4* src = (const uint4*)(Wcat + b_goff + k0);
      uint4 w0 = src[0];
      uint4 w1 = src[1];
      ((uint4*)b_st)[0] = w0;
      ((uint4*)b_st)[1] = w1;
    }
    __syncthreads();
    bf16x8 af[4], bg[4];
    #pragma unroll
    for (int i = 0; i < 4; ++i){ af[i] = *a_rd[i]; bg[i] = *b_rd[i]; }
    #pragma unroll
    for (int mi = 0; mi < 4; ++mi)
      #pragma unroll
      for (int ni = 0; ni < 4; ++ni)
        acc[mi][ni] = __builtin_amdgcn_mfma_f32_16x16x32_bf16(af[mi], bg[ni], acc[mi][ni], 0, 0, 0);
    __syncthreads();
  }

  const int brow = (mtile * 128) >> 11;
  const float* decb = dec + brow * 1024;
  const int colbase = ntile * 128 + wn * 64 + low;
  float dv[4], wc4[4], vw4[4];
  #pragma unroll
  for (int ni = 0; ni < 4; ++ni){
    int col = colbase + ni * 16;
    dv[ni]  = decb[col];
    wc4[ni] = Wc[col];
    vw4[ni] = vw[col];
  }
  const size_t growbase = (size_t)mtile * 128;
  const int rowloc0 = wm * 64 + quad * 4;
  #pragma unroll
  for (int mi = 0; mi < 4; ++mi){
    #pragma unroll
    for (int r = 0; r < 4; ++r){
      int rl = rowloc0 + mi * 16 + r;
      float cv = cov[growbase + rl];
      float s = 0.f;
      #pragma unroll
      for (int ni = 0; ni < 4; ++ni){
        float x = acc[mi][ni][r] + dv[ni] + cv * wc4[ni];
        s += vw4[ni] * fast_tanh(x);
      }
      #pragma unroll
      for (int d = 1; d < 16; d <<= 1) s += __shfl_xor(s, d);
      if (low == 0) ssum[wn][rl] = s;
    }
  }
  __syncthreads();
  if (tid < 128)
    scoresP[(size_t)ntile * Msz + growbase + tid] = ssum[0][tid] + ssum[1][tid];
}

// ---------------------------------------------------------------------------
// Kernel 4: masked renormalized softmax (softmax denom cancels) + coverage_out
// ---------------------------------------------------------------------------
__global__ __launch_bounds__(256) void softmax_kernel(
    const float* __restrict__ scoresP, const float* __restrict__ mask,
    const float* __restrict__ cov, float* __restrict__ attn_o,
    float* __restrict__ cov_o)
{
  const int b = blockIdx.x;
  const int tid = threadIdx.x;
  const int wave = tid >> 6, lane = tid & 63;
  __shared__ float redm[4], reds[4];
  float sc[8];
  float mx = -3.4e38f;
  #pragma unroll
  for (int j = 0; j < 8; ++j){
    int t = tid + j * 256;
    float s = 0.f;
    #pragma unroll
    for (int p = 0; p < 8; ++p) s += scoresP[(size_t)p * Msz + b * TKs + t];
    sc[j] = s;
    mx = fmaxf(mx, s);
  }
  #pragma unroll
  for (int d = 1; d < 64; d <<= 1) mx = fmaxf(mx, __shfl_xor(mx, d));
  if (lane == 0) redm[wave] = mx;
  __syncthreads();
  mx = fmaxf(fmaxf(redm[0], redm[1]), fmaxf(redm[2], redm[3]));
  float e[8]; float sum = 0.f;
  #pragma unroll
  for (int j = 0; j < 8; ++j){
    int t = tid + j * 256;
    float v = __expf(sc[j] - mx) * mask[b * TKs + t];
    e[j] = v; sum += v;
  }
  #pragma unroll
  for (int d = 1; d < 64; d <<= 1) sum += __shfl_xor(sum, d);
  if (lane == 0) reds[wave] = sum;
  __syncthreads();
  sum = reds[0] + reds[1] + reds[2] + reds[3];
  float inv = 1.f / sum;
  #pragma unroll
  for (int j = 0; j < 8; ++j){
    int t = tid + j * 256;
    float a = e[j] * inv;
    attn_o[b * TKs + t] = a;
    cov_o[b * TKs + t]  = cov[b * TKs + t] + a;
  }
}

// ---------------------------------------------------------------------------
// Kernel 5: c_t partials (bf16 h from Acat) + fp32 fallback + reduce
// ---------------------------------------------------------------------------
__global__ __launch_bounds__(256) void ct_partial_bf(
    const unsigned short* __restrict__ Acat, const float* __restrict__ attn,
    float* __restrict__ P)
{
  const int b = blockIdx.y, tc = blockIdx.x;
  const int c4 = threadIdx.x * 4;
  float4 acc = {0.f, 0.f, 0.f, 0.f};
  const size_t rbase = (size_t)b * TKs + tc * 64;
  const float* ab = attn + b * TKs + tc * 64;
  #pragma unroll 4
  for (int tt = 0; tt < 64; ++tt){
    float a = ab[tt];
    uint2 v = *(const uint2*)(Acat + (rbase + tt) * 2048 + c4);
    acc.x += a * __uint_as_float(v.x << 16);
    acc.y += a * __uint_as_float(v.x & 0xffff0000u);
    acc.z += a * __uint_as_float(v.y << 16);
    acc.w += a * __uint_as_float(v.y & 0xffff0000u);
  }
  *(float4*)(P + ((size_t)(tc * Bsz + b)) * Nf + c4) = acc;
}

__global__ __launch_bounds__(256) void ct_partial(
    const float* __restrict__ h, const float* __restrict__ attn,
    float* __restrict__ P)
{
  const int b = blockIdx.y, tc = blockIdx.x;
  const int n4 = threadIdx.x * 4;
  float4 acc = {0.f, 0.f, 0.f, 0.f};
  const float* hb = h + ((size_t)b * TKs + tc * 64) * Nf;
  const float* ab = attn + b * TKs + tc * 64;
  #pragma unroll 4
  for (int tt = 0; tt < 64; ++tt){
    float a = ab[tt];
    float4 hv = *(const float4*)(hb + (size_t)tt * Nf + n4);
    acc.x += a * hv.x; acc.y += a * hv.y; acc.z += a * hv.z; acc.w += a * hv.w;
  }
  *(float4*)(P + ((size_t)(tc * Bsz + b)) * Nf + n4) = acc;
}

__global__ __launch_bounds__(256) void ct_reduce(
    const float* __restrict__ P, float* __restrict__ out)
{
  int bn = (blockIdx.x * 256 + threadIdx.x) * 4;
  float4 s = {0.f, 0.f, 0.f, 0.f};
  for (int j = 0; j < 32; ++j){
    float4 v = *(const float4*)(P + (size_t)j * (Bsz * Nf) + bn);
    s.x += v.x; s.y += v.y; s.z += v.z; s.w += v.w;
  }
  *(float4*)(out + bn) = s;
}

// ---------------------------------------------------------------------------
extern "C" void kernel_launch(void* const* d_in, const int* in_sizes, int n_in,
                              void* d_out, int out_size, void* d_ws, size_t ws_size,
                              hipStream_t stream) {
  const float* s_t  = (const float*)d_in[0];
  const float* h    = (const float*)d_in[1];
  const float* mask = (const float*)d_in[2];
  const float* cov  = (const float*)d_in[3];
  const float* qh   = (const float*)d_in[4];
  const float* Wh   = (const float*)d_in[5];
  const float* Wq   = (const float*)d_in[6];
  const float* Wc   = (const float*)d_in[7];
  const float* Wd   = (const float*)d_in[8];
  const float* bd   = (const float*)d_in[9];
  const float* vw   = (const float*)d_in[10];

  float* out    = (float*)d_out;
  float* c_t    = out;                 // [32,1024]
  float* attn_o = out + Bsz * Nf;      // [32,2048]
  float* cov_o  = attn_o + Bsz * TKs;  // [32,2048]

  char* ws = (char*)d_ws;
  unsigned short* Wcat = (unsigned short*)ws;                      // 4 MB
  float* dec     = (float*)(ws + (4u << 20));                      // 128 KB
  float* scoresP = (float*)(ws + (4u << 20) + (128u << 10));       // 2 MB
  float* ctP     = (float*)(ws + (6u << 20) + (128u << 10));       // 4 MB
  unsigned short* Acat = (unsigned short*)(ws + (16ull << 20));    // 268.4 MB

  const size_t need_fast = (16ull << 20) + (size_t)Msz * KTOT * 2;
  const bool fast = (ws_size >= need_fast);

  hipLaunchKernelGGL(pack_w_kernel, dim3(2048), dim3(256), 0, stream, Wh, Wq, Wcat);
  hipLaunchKernelGGL(dec_kernel,    dim3(16, 32), dim3(256), 0, stream, s_t, Wd, bd, dec);
  if (fast){
    hipLaunchKernelGGL(pack_a_kernel, dim3((unsigned)((size_t)Msz * KTOT / 8 / 256)),
                       dim3(256), 0, stream, h, qh, Acat);
    hipLaunchKernelGGL(gemm_fused_fast, dim3(4096), dim3(256), 0, stream,
                       Acat, Wcat, dec, cov, Wc, vw, scoresP);
  } else {
    hipLaunchKernelGGL(gemm_fused_fb, dim3(8, 512), dim3(256), 0, stream,
                       h, qh, Wcat, dec, cov, Wc, vw, scoresP);
  }
  hipLaunchKernelGGL(softmax_kernel, dim3(32), dim3(256), 0, stream,
                     scoresP, mask, cov, attn_o, cov_o);
  if (fast){
    hipLaunchKernelGGL(ct_partial_bf, dim3(32, 32), dim3(256), 0, stream, Acat, attn_o, ctP);
  } else {
    hipLaunchKernelGGL(ct_partial, dim3(32, 32), dim3(256), 0, stream, h, attn_o, ctP);
  }
  hipLaunchKernelGGL(ct_reduce,  dim3(32), dim3(256), 0, stream, ctP, c_t);
}